// Round 6
// baseline (189.633 us; speedup 1.0000x reference)
//
#include <hip/hip_runtime.h>
#include <hip/hip_bf16.h>
#include <hip/hip_cooperative_groups.h>
#include <math.h>

namespace cg = cooperative_groups;

#define B_  4
#define R_  64
#define C_  192
#define WN_ 16

// B (weights) fragment-major: Wl[b][tap][kc][co][ci32] (bf16)
//   short index = (((b*9+tap)*6+kc)*192 + co)*32 + (ci%32)
// A (input) staged per-block into LDS: Asm[r0..2][kcl0..2][px0..65][ci32] bf16

typedef __attribute__((ext_vector_type(8))) short short8;
typedef __attribute__((ext_vector_type(4))) float floatx4;

static __device__ __forceinline__ unsigned short f2bf(float f) {
    union { float f; unsigned u; } v; v.f = f;
    unsigned r = v.u + 0x7fffu + ((v.u >> 16) & 1u);
    return (unsigned short)(r >> 16);
}

// ---------------------------------------------------------------------------
// One cooperative kernel, 256 blocks x 256 threads, 3 phases + 2 grid syncs.
// Phase 0: pool partials (b,win,quarter) -> w0p[256]
// Phase 1: gates (tiny MLP, redundant per block) + W_eff -> Wl (fragment-major)
//          block = (b, co-triple); conv1_w staged per-win into LDS (dbuf)
// Phase 2: dense 3x3 conv as implicit GEMM (v3 structure): block = (b,h) row,
//          4 waves, wave = 64px x 48co (m4 x n3), A via LDS bf16 fragments in
//          two kc-phases, B depth-2 global ring, XCD swizzle.
// ---------------------------------------------------------------------------
__global__ __launch_bounds__(256, 1) void fused_kernel(
        const float* __restrict__ x,
        const float* __restrict__ conv1_w,
        const float* __restrict__ dc_w,
        const float* __restrict__ dc_b,
        const float* __restrict__ l1_w,
        const float* __restrict__ l1_b,
        const float* __restrict__ l2_w,
        const float* __restrict__ l2_b,
        const float* __restrict__ gk_w,
        const float* __restrict__ gk_b,
        const float* __restrict__ fusion_w,
        const float* __restrict__ fusion_b,
        float* __restrict__ out,
        float* __restrict__ w0p,
        unsigned short* __restrict__ Wl) {
    __shared__ __align__(16) unsigned char smem[3 * 3 * 66 * 32 * 2];  // 38,016 B
    cg::grid_group grid = cg::this_grid();
    const int bi = blockIdx.x;
    const int tid = threadIdx.x;

    // ================= Phase 0: pool partials =================
    {
        float* part = (float*)smem;
        int b = bi >> 6, rest = bi & 63, win = rest >> 2, q = rest & 3;
        int wr = win >> 2, wc = win & 3;
        if (tid < 192) {
            const float* xb = x + ((size_t)b * 4096) * C_ + tid;
            float Wsum = 0.f, Rtop = 0.f, Rbot = 0.f, Cleft = 0.f, Cright = 0.f;
            float c00 = 0.f, c0F = 0.f, cF0 = 0.f, cFF = 0.f;
            #pragma unroll
            for (int pr = 0; pr < 4; ++pr) {
                int h = wr * 16 + q * 4 + pr;
                #pragma unroll
                for (int pw = 0; pw < 16; ++pw) {
                    int w = wc * 16 + pw;
                    float v = xb[(size_t)(h * 64 + w) * C_];
                    Wsum += v;
                    if (q == 0 && pr == 0) { Rtop += v; if (pw == 0) c00 = v; if (pw == 15) c0F = v; }
                    if (q == 3 && pr == 3) { Rbot += v; if (pw == 0) cF0 = v; if (pw == 15) cFF = v; }
                    if (pw == 0)  Cleft  += v;
                    if (pw == 15) Cright += v;
                }
            }
            const float* kp = conv1_w + ((size_t)(win * C_ + tid)) * 9;
            float pooled = 0.f;
            #pragma unroll
            for (int i = 0; i < 3; ++i) {
                #pragma unroll
                for (int j = 0; j < 3; ++j) {
                    int di = i - 1, dj = j - 1;
                    float S = Wsum;
                    if (di == -1) S -= Rbot;   else if (di == 1) S -= Rtop;
                    if (dj == -1) S -= Cright; else if (dj == 1) S -= Cleft;
                    if (di == -1 && dj == -1) S += cFF;
                    if (di == -1 && dj ==  1) S += cF0;
                    if (di ==  1 && dj == -1) S += c0F;
                    if (di ==  1 && dj ==  1) S += c00;
                    pooled += kp[i * 3 + j] * S;
                }
            }
            float val = (pooled * (1.f / 256.f)) * dc_w[win * C_ + tid];
            for (int off = 32; off; off >>= 1) val += __shfl_down(val, off, 64);
            if ((tid & 63) == 0) part[tid >> 6] = val;
        }
        __syncthreads();
        if (tid == 0) w0p[bi] = part[0] + part[1] + part[2];
    }
    grid.sync();

    // ================= Phase 1: gates + W_eff =================
    {
        float* hbuf = (float*)smem;        // 64
        float* s_sh = hbuf + 64;           // 16
        float* cw   = s_sh + 16;           // 2 x 1728 floats (win-slice dbuf)
        const int b = bi >> 6, cog = bi & 63;
        const int co0 = cog * 3;

        if (tid < 64) {
            float a = l1_b[tid];
            #pragma unroll
            for (int w = 0; w < 16; ++w) {
                float w0 = w0p[b * 64 + w * 4 + 0] + w0p[b * 64 + w * 4 + 1]
                         + w0p[b * 64 + w * 4 + 2] + w0p[b * 64 + w * 4 + 3];
                a += (w0 + dc_b[w]) * l1_w[tid * 16 + w];
            }
            hbuf[tid] = 0.5f * a * (1.f + erff(a * 0.70710678118654752f));
        }
        __syncthreads();
        if (tid < 16) {
            float a2 = l2_b[tid];
            #pragma unroll
            for (int k = 0; k < 64; ++k) a2 += hbuf[k] * l2_w[tid * 64 + k];
            s_sh[tid] = 1.f / (1.f + expf(-a2));
        }

        const int ci = tid;
        const bool act = tid < 192;
        float fg[3];
        float acc[3][9];
        if (act) {
            float gb = gk_b[0];
            #pragma unroll
            for (int g = 0; g < 3; ++g) {
                fg[g] = fusion_w[(size_t)(co0 + g) * 3264 + 16 * C_ + ci];
                #pragma unroll
                for (int t = 0; t < 9; ++t) acc[g][t] = fg[g] * gb;
            }
            // stage win 0 slice: cw[0][ci*9+t]
            #pragma unroll
            for (int t = 0; t < 9; ++t)
                cw[ci * 9 + t] = conv1_w[(size_t)(0 * C_ + ci) * 9 + t];
        }
        __syncthreads();   // covers s_sh and cw[0]

        for (int w = 0; w < 16; ++w) {
            const int buf = w & 1, nbuf = buf ^ 1;
            if (w < 15 && act) {
                #pragma unroll
                for (int t = 0; t < 9; ++t)
                    cw[nbuf * 1728 + ci * 9 + t] =
                        conv1_w[(size_t)((w + 1) * C_ + ci) * 9 + t];
            }
            if (act) {
                const float sw = s_sh[w], gw = gk_w[w];
                float coef[3];
                #pragma unroll
                for (int g = 0; g < 3; ++g)
                    coef[g] = (fusion_w[(size_t)(co0 + g) * 3264 + w * C_ + ci]
                               + fg[g] * gw) * sw;
                #pragma unroll
                for (int t = 0; t < 9; ++t) {
                    const float k = cw[buf * 1728 + ci * 9 + t];
                    #pragma unroll
                    for (int g = 0; g < 3; ++g) acc[g][t] += coef[g] * k;
                }
            }
            __syncthreads();
        }
        if (act) {
            const int kc = ci >> 5, cio = ci & 31;
            #pragma unroll
            for (int g = 0; g < 3; ++g)
                #pragma unroll
                for (int t = 0; t < 9; ++t)
                    Wl[((((size_t)(b * 9 + t)) * 6 + kc) * C_ + co0 + g) * 32 + cio]
                        = f2bf(acc[g][t]);
        }
    }
    grid.sync();

    // ================= Phase 2: conv (implicit GEMM) =================
    {
        unsigned short* Asm = (unsigned short*)smem;
        const int g = (bi & 7) * 32 + (bi >> 3);       // XCD swizzle
        const int b = g >> 6, h = g & 63;
        const int wv = tid >> 6, lane = tid & 63;
        const int lo = lane & 15, quad = lane >> 4;
        const int n0 = wv * 48;

        const short* wp = (const short*)Wl;
        int Bbase[3];
        #pragma unroll
        for (int nt = 0; nt < 3; ++nt)
            Bbase[nt] = (b * 54 * C_ + n0 + nt * 16 + lo) * 32 + quad * 8;
        int Alds[4];
        #pragma unroll
        for (int mt = 0; mt < 4; ++mt)
            Alds[mt] = (mt * 16 + lo + 1) * 32 + quad * 8;

        floatx4 acc[4][3];
        #pragma unroll
        for (int mt = 0; mt < 4; ++mt)
            #pragma unroll
            for (int nt = 0; nt < 3; ++nt)
                acc[mt][nt] = (floatx4){0.f, 0.f, 0.f, 0.f};

        #pragma unroll
        for (int ph = 0; ph < 2; ++ph) {
            const int kc0 = ph * 3;
            #pragma unroll
            for (int r = 0; r < 3; ++r) {
                int hr = h - 1 + r;
                unsigned short* Lr = Asm + r * (3 * 66 * 32);
                if (hr >= 0 && hr < 64) {
                    const float* src = x + ((size_t)(b * 4096 + hr * 64)) * C_ + kc0 * 32;
                    #pragma unroll
                    for (int it = 0; it < 3; ++it) {
                        int c = tid + it * 256;               // < 768
                        int px = c / 12, sub = c % 12;
                        int kcl = sub >> 2, ci0 = (sub & 3) * 8;
                        const float* p = src + px * C_ + kcl * 32 + ci0;
                        float4 v0 = *(const float4*)p;
                        float4 v1 = *(const float4*)(p + 4);
                        short8 o;
                        o[0] = (short)f2bf(v0.x); o[1] = (short)f2bf(v0.y);
                        o[2] = (short)f2bf(v0.z); o[3] = (short)f2bf(v0.w);
                        o[4] = (short)f2bf(v1.x); o[5] = (short)f2bf(v1.y);
                        o[6] = (short)f2bf(v1.z); o[7] = (short)f2bf(v1.w);
                        *(short8*)(Lr + (kcl * 66 + px + 1) * 32 + ci0) = o;
                    }
                } else {
                    for (int c = tid; c < 792; c += 256)
                        *(short8*)(Lr + c * 8) = (short8){0, 0, 0, 0, 0, 0, 0, 0};
                }
            }
            if (tid < 72) {   // halo columns px=0,65
                int loc = tid >> 2, j = tid & 3;
                int r = loc / 6, rem = loc % 6, kcl = rem >> 1, px = (rem & 1) * 65;
                *(short8*)(Asm + ((r * 3 + kcl) * 66 + px) * 32 + j * 8) =
                    (short8){0, 0, 0, 0, 0, 0, 0, 0};
            }
            __syncthreads();

            short8 Bb[3][3], Ab[2][4];
            auto loadB = [&](int t27, int slot) {
                int tap = t27 / 3, kcl = t27 % 3;
                int s = tap * 6 + kc0 + kcl;
                #pragma unroll
                for (int nt = 0; nt < 3; ++nt)
                    Bb[slot][nt] = *(const short8*)(wp + Bbase[nt] + s * (C_ * 32));
            };
            auto loadA = [&](int t27, int slot) {
                int tap = t27 / 3, kcl = t27 % 3;
                int dh = tap / 3, dw = tap % 3 - 1;
                int base = ((dh * 3 + kcl) * 66 + dw) * 32;
                #pragma unroll
                for (int mt = 0; mt < 4; ++mt)
                    Ab[slot][mt] = *(const short8*)((const short*)Asm + base + Alds[mt]);
            };
            loadB(0, 0); loadB(1, 1); loadA(0, 0);
            #pragma unroll
            for (int t = 0; t < 27; ++t) {
                const int bc = t % 3, ac = t & 1;
                if (t + 2 < 27) loadB(t + 2, (t + 2) % 3);
                if (t + 1 < 27) loadA(t + 1, ac ^ 1);
                #pragma unroll
                for (int mt = 0; mt < 4; ++mt)
                    #pragma unroll
                    for (int nt = 0; nt < 3; ++nt)
                        acc[mt][nt] = __builtin_amdgcn_mfma_f32_16x16x32_bf16(
                            Ab[ac][mt], Bb[bc][nt], acc[mt][nt], 0, 0, 0);
            }
            __syncthreads();
        }

        #pragma unroll
        for (int nt = 0; nt < 3; ++nt) {
            const int co = n0 + nt * 16 + lo;
            const float fb = fusion_b[co];
            #pragma unroll
            for (int mt = 0; mt < 4; ++mt) {
                #pragma unroll
                for (int r = 0; r < 4; ++r) {
                    const int px = mt * 16 + quad * 4 + r;
                    out[((size_t)(b * 4096 + h * 64 + px)) * C_ + co] = acc[mt][nt][r] + fb;
                }
            }
        }
    }
}

// ---------------------------------------------------------------------------
extern "C" void kernel_launch(void* const* d_in, const int* in_sizes, int n_in,
                              void* d_out, int out_size, void* d_ws, size_t ws_size,
                              hipStream_t stream) {
    const float* x        = (const float*)d_in[0];
    const float* conv1_w  = (const float*)d_in[1];
    const float* dc_w     = (const float*)d_in[2];
    const float* dc_b     = (const float*)d_in[3];
    const float* l1_w     = (const float*)d_in[4];
    const float* l1_b     = (const float*)d_in[5];
    const float* l2_w     = (const float*)d_in[6];
    const float* l2_b     = (const float*)d_in[7];
    const float* gk_w     = (const float*)d_in[8];
    const float* gk_b     = (const float*)d_in[9];
    const float* fusion_w = (const float*)d_in[10];
    const float* fusion_b = (const float*)d_in[11];
    float* out = (float*)d_out;

    char* ws = (char*)d_ws;
    float* w0p = (float*)ws;                                   // 256 floats
    unsigned short* Wl = (unsigned short*)(ws + 1024);         // 2,654,208 B

    void* args[] = {
        (void*)&x, (void*)&conv1_w, (void*)&dc_w, (void*)&dc_b,
        (void*)&l1_w, (void*)&l1_b, (void*)&l2_w, (void*)&l2_b,
        (void*)&gk_w, (void*)&gk_b, (void*)&fusion_w, (void*)&fusion_b,
        (void*)&out, (void*)&w0p, (void*)&Wl
    };
    hipLaunchCooperativeKernel((void*)fused_kernel, dim3(256), dim3(256),
                               args, 0, stream);
}

// Round 7
// 120.105 us; speedup vs baseline: 1.5789x; 1.5789x over previous
//
#include <hip/hip_runtime.h>
#include <hip/hip_bf16.h>
#include <math.h>

#define B_  4
#define R_  64
#define C_  192
#define WN_ 16

// B (weights) fragment-major: Wl[b][tap][kc][co][ci32] (bf16)
//   short index = (((b*9+tap)*6+kc)*192 + co)*32 + (ci%32)
// A staged per conv block into LDS: Asm[r0..5][kcl0..1][px0..65][ci32] bf16

typedef __attribute__((ext_vector_type(8))) short short8;
typedef __attribute__((ext_vector_type(4))) float floatx4;

static __device__ __forceinline__ unsigned short f2bf(float f) {
    union { float f; unsigned u; } v; v.f = f;
    unsigned r = v.u + 0x7fffu + ((v.u >> 16) & 1u);
    return (unsigned short)(r >> 16);
}

// ---------------------------------------------------------------------------
// Kernel 1: blocks [0,256) = pool partials (one quarter-window each),
// blocks [256,310) = conv1_w transpose to cw_t[tap][win][ci].
// ---------------------------------------------------------------------------
__global__ __launch_bounds__(256) void pre_kernel(
        const float* __restrict__ x,
        const float* __restrict__ conv1_w,
        const float* __restrict__ dc_w,
        float* __restrict__ w0p,
        float* __restrict__ cw_t) {
    __shared__ float part[3];
    int blk = blockIdx.x;
    int tid = threadIdx.x;

    if (blk < 256) {
        int b = blk >> 6, rest = blk & 63, win = rest >> 2, q = rest & 3;
        int wr = win >> 2, wc = win & 3;
        if (tid < 192) {
            const float* xb = x + ((size_t)b * 4096) * C_ + tid;
            float Wsum = 0.f, Rtop = 0.f, Rbot = 0.f, Cleft = 0.f, Cright = 0.f;
            float c00 = 0.f, c0F = 0.f, cF0 = 0.f, cFF = 0.f;
            #pragma unroll
            for (int pr = 0; pr < 4; ++pr) {
                int h = wr * 16 + q * 4 + pr;
                #pragma unroll
                for (int pw = 0; pw < 16; ++pw) {
                    int w = wc * 16 + pw;
                    float v = xb[(size_t)(h * 64 + w) * C_];
                    Wsum += v;
                    if (q == 0 && pr == 0) { Rtop += v; if (pw == 0) c00 = v; if (pw == 15) c0F = v; }
                    if (q == 3 && pr == 3) { Rbot += v; if (pw == 0) cF0 = v; if (pw == 15) cFF = v; }
                    if (pw == 0)  Cleft  += v;
                    if (pw == 15) Cright += v;
                }
            }
            const float* kp = conv1_w + ((size_t)(win * C_ + tid)) * 9;
            float pooled = 0.f;
            #pragma unroll
            for (int i = 0; i < 3; ++i) {
                #pragma unroll
                for (int j = 0; j < 3; ++j) {
                    int di = i - 1, dj = j - 1;
                    float S = Wsum;
                    if (di == -1) S -= Rbot;   else if (di == 1) S -= Rtop;
                    if (dj == -1) S -= Cright; else if (dj == 1) S -= Cleft;
                    if (di == -1 && dj == -1) S += cFF;
                    if (di == -1 && dj ==  1) S += cF0;
                    if (di ==  1 && dj == -1) S += c0F;
                    if (di ==  1 && dj ==  1) S += c00;
                    pooled += kp[i * 3 + j] * S;
                }
            }
            float val = (pooled * (1.f / 256.f)) * dc_w[win * C_ + tid];
            for (int off = 32; off; off >>= 1) val += __shfl_down(val, off, 64);
            if ((tid & 63) == 0) part[tid >> 6] = val;
        }
        __syncthreads();
        if (tid == 0) w0p[blk] = part[0] + part[1] + part[2];
    } else {
        int basei = (blk - 256) * 512 + tid * 2;   // 54*512 = 27648 elements
        #pragma unroll
        for (int e = 0; e < 2; ++e) {
            int o = basei + e;
            int t = o / 3072;
            int r = o - t * 3072;                  // win*192+ci
            cw_t[o] = conv1_w[(size_t)r * 9 + t];
        }
    }
}

// ---------------------------------------------------------------------------
// Kernel 2: gates (tiny MLP, redundant per block) + effective dense conv
// weights in fragment-major bf16 layout Wl[b][tap][kc][co][ci32].
// ---------------------------------------------------------------------------
__global__ __launch_bounds__(192) void weff_kernel(
        const float* __restrict__ cw_t,
        const float* __restrict__ gk_w,
        const float* __restrict__ gk_b,
        const float* __restrict__ fusion_w,
        const float* __restrict__ w0p,
        const float* __restrict__ dc_b,
        const float* __restrict__ l1_w,
        const float* __restrict__ l1_b,
        const float* __restrict__ l2_w,
        const float* __restrict__ l2_b,
        unsigned short* __restrict__ Wl) {
    __shared__ float hbuf[64];
    __shared__ float s_sh[16];
    int blk = blockIdx.x;             // b*192 + co
    int b = blk / C_, co = blk % C_;
    int tid = threadIdx.x;            // 0..191

    if (tid < 64) {
        float a = l1_b[tid];
        #pragma unroll
        for (int w = 0; w < 16; ++w) {
            float w0 = w0p[b * 64 + w * 4 + 0] + w0p[b * 64 + w * 4 + 1]
                     + w0p[b * 64 + w * 4 + 2] + w0p[b * 64 + w * 4 + 3];
            a += (w0 + dc_b[w]) * l1_w[tid * 16 + w];
        }
        hbuf[tid] = 0.5f * a * (1.f + erff(a * 0.70710678118654752f));
    }
    __syncthreads();
    if (tid < 16) {
        float a2 = l2_b[tid];
        #pragma unroll
        for (int k = 0; k < 64; ++k) a2 += hbuf[k] * l2_w[tid * 64 + k];
        s_sh[tid] = 1.f / (1.f + expf(-a2));
    }
    __syncthreads();

    int ci = tid;
    float fg = fusion_w[(size_t)co * 3264 + 16 * C_ + ci];
    float acc[9];
    float g0 = fg * gk_b[0];
    #pragma unroll
    for (int t = 0; t < 9; ++t) acc[t] = g0;
    for (int w = 0; w < 16; ++w) {
        float coef = (fusion_w[(size_t)co * 3264 + w * C_ + ci] + fg * gk_w[w]) * s_sh[w];
        #pragma unroll
        for (int t = 0; t < 9; ++t)
            acc[t] += coef * cw_t[t * 3072 + w * C_ + ci];
    }
    #pragma unroll
    for (int t = 0; t < 9; ++t) {
        int kc = ci >> 5, cio = ci & 31;
        Wl[((((size_t)(b * 9 + t)) * 6 + kc) * C_ + co) * 32 + cio] = f2bf(acc[t]);
    }
}

// ---------------------------------------------------------------------------
// Kernel 3 (v4): dense 3x3 conv, implicit GEMM, 4 output rows per block.
// Block = (b, strip of 4 rows, co-quarter of 48). 256 threads = 4 waves;
// wave wv computes output row h0+wv (m=4 x n=3 -> 12 MFMA/step) from a
// SHARED 6-row LDS window. vs v3: waves read DISTINCT rows (LDS bytes per
// output row 4x lower) and all share the same B fragments (L1 broadcast;
// B L2 traffic 4x lower). K split into 3 kc-phases of 64 ci; LDS = 50.7 KB.
// Grid 256 = 1 block/CU. XCD swizzle: each XCD serves one batch's Wl slice.
// ---------------------------------------------------------------------------
__global__ __launch_bounds__(256, 1) void conv_kernel(
        const float* __restrict__ x,
        const unsigned short* __restrict__ Wl,
        const float* __restrict__ fusion_b,
        float* __restrict__ out) {
    __shared__ unsigned short Asm[6 * 2 * 66 * 32];   // 50,688 B
    const int bi = blockIdx.x;
    const int xcd = bi & 7, l = bi >> 3;
    const int b = xcd >> 1;
    const int strip = (xcd & 1) * 8 + (l >> 2);
    const int coq = l & 3;
    const int h0 = strip * 4;
    const int tid = threadIdx.x;
    const int wv = tid >> 6, lane = tid & 63;
    const int lo = lane & 15, quad = lane >> 4;

    const short* wp = (const short*)Wl;
    int Bbase[3];
    #pragma unroll
    for (int nt = 0; nt < 3; ++nt)
        Bbase[nt] = (b * 54 * C_ + coq * 48 + nt * 16 + lo) * 32 + quad * 8;
    int Alds[4];
    #pragma unroll
    for (int mt = 0; mt < 4; ++mt)
        Alds[mt] = (mt * 16 + lo + 1) * 32 + quad * 8;

    floatx4 acc[4][3];
    #pragma unroll
    for (int mt = 0; mt < 4; ++mt)
        #pragma unroll
        for (int nt = 0; nt < 3; ++nt)
            acc[mt][nt] = (floatx4){0.f, 0.f, 0.f, 0.f};

    #pragma unroll
    for (int p = 0; p < 3; ++p) {
        // ---- stage 6 input rows x 64 ci (2 kc-chunks) into LDS ----
        #pragma unroll
        for (int r = 0; r < 6; ++r) {
            int hr = h0 - 1 + r;
            unsigned short* Lr = Asm + r * (2 * 66 * 32);
            if (hr >= 0 && hr < 64) {
                const float* src = x + ((size_t)(b * 4096 + hr * 64)) * C_ + p * 64;
                #pragma unroll
                for (int it = 0; it < 2; ++it) {
                    int c = tid + it * 256;          // < 512
                    int px = c >> 3, sub = c & 7;
                    int kcl = sub >> 2, ci0 = (sub & 3) * 8;
                    const float* pp = src + px * C_ + kcl * 32 + ci0;
                    float4 v0 = *(const float4*)pp;
                    float4 v1 = *(const float4*)(pp + 4);
                    short8 o;
                    o[0] = (short)f2bf(v0.x); o[1] = (short)f2bf(v0.y);
                    o[2] = (short)f2bf(v0.z); o[3] = (short)f2bf(v0.w);
                    o[4] = (short)f2bf(v1.x); o[5] = (short)f2bf(v1.y);
                    o[6] = (short)f2bf(v1.z); o[7] = (short)f2bf(v1.w);
                    *(short8*)(Lr + (kcl * 66 + px + 1) * 32 + ci0) = o;
                }
            } else {
                for (int c = tid; c < 528; c += 256)
                    *(short8*)(Lr + c * 8) = (short8){0, 0, 0, 0, 0, 0, 0, 0};
            }
        }
        // halo columns px=0,65: 6 rows x 2 kcl x 2 sides x 4 j-chunks = 96
        if (tid < 96) {
            int loc = tid >> 2, j = tid & 3;
            int r = loc >> 2, rem = loc & 3, kcl = rem >> 1, px = (rem & 1) * 65;
            *(short8*)(Asm + r * (2 * 66 * 32) + (kcl * 66 + px) * 32 + j * 8) =
                (short8){0, 0, 0, 0, 0, 0, 0, 0};
        }
        __syncthreads();

        // ---- 18 K-steps: taps 0..8 x kcl 0..1 ----
        short8 Bb[3][3], Ab[2][4];
        auto loadB = [&](int t18, int slot) {
            int tap = t18 >> 1, kcl = t18 & 1;
            int sg = tap * 6 + p * 2 + kcl;
            #pragma unroll
            for (int nt = 0; nt < 3; ++nt)
                Bb[slot][nt] = *(const short8*)(wp + Bbase[nt] + sg * (C_ * 32));
        };
        auto loadA = [&](int t18, int slot) {
            int tap = t18 >> 1, kcl = t18 & 1;
            int dh = tap / 3, dw = tap % 3 - 1;
            int base = ((wv + dh) * 2 + kcl) * (66 * 32) + dw * 32;
            #pragma unroll
            for (int mt = 0; mt < 4; ++mt)
                Ab[slot][mt] = *(const short8*)((const short*)Asm + base + Alds[mt]);
        };
        loadB(0, 0); loadB(1, 1); loadA(0, 0);
        #pragma unroll
        for (int t = 0; t < 18; ++t) {
            const int bc = t % 3, ac = t & 1;
            if (t + 2 < 18) loadB(t + 2, (t + 2) % 3);
            if (t + 1 < 18) loadA(t + 1, ac ^ 1);
            #pragma unroll
            for (int mt = 0; mt < 4; ++mt)
                #pragma unroll
                for (int nt = 0; nt < 3; ++nt)
                    acc[mt][nt] = __builtin_amdgcn_mfma_f32_16x16x32_bf16(
                        Ab[ac][mt], Bb[bc][nt], acc[mt][nt], 0, 0, 0);
        }
        __syncthreads();   // LDS reads done before next phase restages
    }

    // ---- epilogue: wave wv owns output row h0+wv ----
    const int h = h0 + wv;
    #pragma unroll
    for (int nt = 0; nt < 3; ++nt) {
        const int co = coq * 48 + nt * 16 + lo;
        const float fb = fusion_b[co];
        #pragma unroll
        for (int mt = 0; mt < 4; ++mt) {
            #pragma unroll
            for (int r = 0; r < 4; ++r) {
                const int px = mt * 16 + quad * 4 + r;
                out[((size_t)(b * 4096 + h * 64 + px)) * C_ + co] = acc[mt][nt][r] + fb;
            }
        }
    }
}

// ---------------------------------------------------------------------------
extern "C" void kernel_launch(void* const* d_in, const int* in_sizes, int n_in,
                              void* d_out, int out_size, void* d_ws, size_t ws_size,
                              hipStream_t stream) {
    const float* x        = (const float*)d_in[0];
    const float* conv1_w  = (const float*)d_in[1];
    const float* dc_w     = (const float*)d_in[2];
    const float* dc_b     = (const float*)d_in[3];
    const float* l1_w     = (const float*)d_in[4];
    const float* l1_b     = (const float*)d_in[5];
    const float* l2_w     = (const float*)d_in[6];
    const float* l2_b     = (const float*)d_in[7];
    const float* gk_w     = (const float*)d_in[8];
    const float* gk_b     = (const float*)d_in[9];
    const float* fusion_w = (const float*)d_in[10];
    const float* fusion_b = (const float*)d_in[11];
    float* out = (float*)d_out;

    char* ws = (char*)d_ws;
    float* w0p  = (float*)ws;                                  // 256 floats
    float* cw_t = (float*)(ws + 1024);                         // 27648 floats
    unsigned short* Wl = (unsigned short*)(ws + 1024 + 110592); // 2,654,208 B

    hipLaunchKernelGGL(pre_kernel, dim3(310), dim3(256), 0, stream,
                       x, conv1_w, dc_w, w0p, cw_t);
    hipLaunchKernelGGL(weff_kernel, dim3(B_ * C_), dim3(192), 0, stream,
                       cw_t, gk_w, gk_b, fusion_w, w0p, dc_b, l1_w, l1_b, l2_w, l2_b, Wl);
    hipLaunchKernelGGL(conv_kernel, dim3(256), dim3(256), 0, stream,
                       x, Wl, fusion_b, out);
}